// Round 5
// baseline (264.012 us; speedup 1.0000x reference)
//
#include <hip/hip_runtime.h>

#define BB 16
#define NN 512
#define DD 256
#define HH 8
#define CC 16

typedef unsigned short u16;
using short8 = __attribute__((ext_vector_type(8))) short;
using f32x4  = __attribute__((ext_vector_type(4))) float;

__device__ __forceinline__ float gelu_f(float x) {
    return 0.5f * x * (1.0f + erff(x * 0.70710678118654752f));
}
__device__ __forceinline__ u16 f2bf(float f) {
    unsigned int u = __float_as_uint(f);
    unsigned int r = u + 0x7FFFu + ((u >> 16) & 1u);
    return (u16)(r >> 16);
}
// async global->LDS, 16B/lane; LDS dest = wave-uniform base + lane*16
__device__ __forceinline__ void gld16(const u16* g, const u16* l) {
    __builtin_amdgcn_global_load_lds(
        (const __attribute__((address_space(1))) unsigned int*)g,
        (__attribute__((address_space(3))) unsigned int*)l, 16, 0, 0);
}

// Q pre-scale: (1/sqrt(32)) * log2(e)  -> attention uses exp2
#define QSCALE 0.25505412f

// ---------------------------------------------------------------------------
// QKV0 GEMM: 64x64 tiles, BK=32, LDS staging. grid (128, 12).
// sel = y>>2 picks Q/K/V; Q,K head-major [b,h,n,32] (Q scaled), V [b,h,32,n].
// ---------------------------------------------------------------------------
__global__ __launch_bounds__(256) void gemm_qkv(
    const u16* __restrict__ A,
    const u16* __restrict__ W0, const u16* __restrict__ W1, const u16* __restrict__ W2,
    u16* __restrict__ O0, u16* __restrict__ O1, u16* __restrict__ O2)
{
    __shared__ __align__(16) u16 As[64 * 32];
    __shared__ __align__(16) u16 Bs[64 * 32];
    const int tid = threadIdx.x, wave = tid >> 6, lane = tid & 63;
    const int col = lane & 15, quad = lane >> 4;
    const int mbase = blockIdx.x * 64;
    const int sel = blockIdx.y >> 2;
    const int nbase = (blockIdx.y & 3) * 64;
    const u16* W = (sel == 0) ? W0 : ((sel == 1) ? W1 : W2);
    u16* O = (sel == 0) ? O0 : ((sel == 1) ? O1 : O2);
    const int srow = lane >> 2, skk = (lane & 3) * 8;
    const int mh = (wave & 1) * 32, nh = (wave >> 1) * 32;

    f32x4 acc[2][2];
#pragma unroll
    for (int i = 0; i < 2; ++i)
#pragma unroll
        for (int j = 0; j < 2; ++j) acc[i][j] = (f32x4){0.f, 0.f, 0.f, 0.f};

    for (int k0 = 0; k0 < DD; k0 += 32) {
        gld16(A + (size_t)(mbase + wave * 16 + srow) * DD + k0 + skk, &As[wave * 512]);
        gld16(W + (size_t)(nbase + wave * 16 + srow) * DD + k0 + skk, &Bs[wave * 512]);
        __syncthreads();
        short8 af[2], bfr[2];
#pragma unroll
        for (int i = 0; i < 2; ++i) af[i]  = *(const short8*)&As[(mh + i * 16 + col) * 32 + quad * 8];
#pragma unroll
        for (int j = 0; j < 2; ++j) bfr[j] = *(const short8*)&Bs[(nh + j * 16 + col) * 32 + quad * 8];
#pragma unroll
        for (int i = 0; i < 2; ++i)
#pragma unroll
            for (int j = 0; j < 2; ++j)
                acc[i][j] = __builtin_amdgcn_mfma_f32_16x16x32_bf16(af[i], bfr[j], acc[i][j], 0, 0, 0);
        __syncthreads();
    }

    const int b = mbase >> 9;
#pragma unroll
    for (int i = 0; i < 2; ++i) {
#pragma unroll
        for (int j = 0; j < 2; ++j) {
            const int ccol = nbase + nh + j * 16 + col;
            const int tok0 = (mbase & 511) + mh + i * 16 + quad * 4;
            const int head = ccol >> 5, dk = ccol & 31;
            if (sel == 2) {
                ushort4 pk;
                pk.x = f2bf(acc[i][j][0]); pk.y = f2bf(acc[i][j][1]);
                pk.z = f2bf(acc[i][j][2]); pk.w = f2bf(acc[i][j][3]);
                *(ushort4*)&O[(((size_t)b * HH + head) * 32 + dk) * NN + tok0] = pk;
            } else {
#pragma unroll
                for (int r = 0; r < 4; ++r) {
                    float v = acc[i][j][r];
                    if (sel == 0) v *= QSCALE;
                    O[(((size_t)b * HH + head) * NN + tok0 + r) * 32 + dk] = f2bf(v);
                }
            }
        }
    }
}

// ---------------------------------------------------------------------------
// Flash MFMA attention, no-max softmax (pre-scaled by log2e/sqrt(dk), exp2).
// grid 1024: gid = qb*128 + (b*8+h) -> q-blocks of a (b,h) share an XCD.
// COLSUM=1: only writes per-block column sums (feeds mean(x2)@Wo1).
// ---------------------------------------------------------------------------
template<int COLSUM>
__global__ __launch_bounds__(256) void attn_mfma(
    const u16* __restrict__ Qh, const u16* __restrict__ Kh,
    const u16* __restrict__ VT, u16* __restrict__ O,
    float* __restrict__ partial)
{
    __shared__ __align__(16) u16 Vt[32 * 520];
    __shared__ __align__(16) u16 Pc[4][16 * 32];
    __shared__ float cs[4][32];
    const int tid = threadIdx.x, wave = tid >> 6, lane = tid & 63;
    const int col = lane & 15, quad = lane >> 4;
    const int gid = blockIdx.x;
    const int qb = gid >> 7, bh = gid & 127;
    const int q0 = qb * 64 + wave * 16;

    const u16* vsrc = VT + (size_t)bh * 32 * NN;
#pragma unroll
    for (int i = 0; i < 8; ++i) {
        const int row = wave + i * 4;
        gld16(vsrc + (size_t)row * NN + lane * 8, &Vt[row * 520]);
    }
    const short8 aq = *(const short8*)(Qh + ((size_t)bh * NN + q0 + col) * 32 + quad * 8);
    __syncthreads();

    const u16* ksrc = Kh + (size_t)bh * NN * 32;
    float l[4] = {0.f, 0.f, 0.f, 0.f};
    f32x4 oacc[2];
    oacc[0] = (f32x4){0.f, 0.f, 0.f, 0.f};
    oacc[1] = (f32x4){0.f, 0.f, 0.f, 0.f};

    for (int g = 0; g < 16; ++g) {
#pragma unroll
        for (int k2 = 0; k2 < 2; ++k2) {
            const int kt = g * 2 + k2;
            const short8 bk = *(const short8*)(ksrc + (size_t)(kt * 16 + col) * 32 + quad * 8);
            f32x4 z = {0.f, 0.f, 0.f, 0.f};
            const f32x4 s = __builtin_amdgcn_mfma_f32_16x16x32_bf16(aq, bk, z, 0, 0, 0);
#pragma unroll
            for (int r = 0; r < 4; ++r) {
                const float p = exp2f(s[r]);
                l[r] += p;
                Pc[wave][(quad * 4 + r) * 32 + k2 * 16 + col] = f2bf(p);
            }
        }
        const short8 ap = *(const short8*)&Pc[wave][col * 32 + quad * 8];
#pragma unroll
        for (int nt = 0; nt < 2; ++nt) {
            const short8 bv = *(const short8*)&Vt[(nt * 16 + col) * 520 + g * 32 + quad * 8];
            oacc[nt] = __builtin_amdgcn_mfma_f32_16x16x32_bf16(ap, bv, oacc[nt], 0, 0, 0);
        }
    }
#pragma unroll
    for (int r = 0; r < 4; ++r) {
        l[r] += __shfl_xor(l[r], 1, 64);
        l[r] += __shfl_xor(l[r], 2, 64);
        l[r] += __shfl_xor(l[r], 4, 64);
        l[r] += __shfl_xor(l[r], 8, 64);
    }
    if (COLSUM) {
        float sv[2] = {0.f, 0.f};
#pragma unroll
        for (int nt = 0; nt < 2; ++nt) {
#pragma unroll
            for (int r = 0; r < 4; ++r) sv[nt] += oacc[nt][r] / l[r];
            sv[nt] += __shfl_xor(sv[nt], 16, 64);
            sv[nt] += __shfl_xor(sv[nt], 32, 64);
        }
        if (lane < 16) { cs[wave][col] = sv[0]; cs[wave][16 + col] = sv[1]; }
        __syncthreads();
        if (tid < 32)
            partial[(size_t)(bh * 8 + qb) * 32 + tid] =
                cs[0][tid] + cs[1][tid] + cs[2][tid] + cs[3][tid];
    } else {
        const int b = bh >> 3, h = bh & 7;
        u16* obase = O + ((size_t)b * NN) * DD + h * 32;
#pragma unroll
        for (int nt = 0; nt < 2; ++nt)
#pragma unroll
            for (int r = 0; r < 4; ++r)
                obase[(size_t)(q0 + quad * 4 + r) * DD + nt * 16 + col] = f2bf(oacc[nt][r] / l[r]);
    }
}

// ---------------------------------------------------------------------------
// Fused X1 + QKV1 for 64 rows/block (grid 128). Phase A: T = gelu(A5@Wo0t)
// into LDS (X1 never hits HBM). Phase B: Q/K/V = T @ W*, B-frags direct from
// L2 (no staging barriers; only 1 barrier in the whole kernel).
// ---------------------------------------------------------------------------
__global__ __launch_bounds__(256) void fused_x1qkv1(
    const u16* __restrict__ A5, const u16* __restrict__ Wo0t,
    const u16* __restrict__ Wq1t, const u16* __restrict__ Wk1t,
    const u16* __restrict__ Wv1t,
    u16* __restrict__ Qh, u16* __restrict__ Kh, u16* __restrict__ VT)
{
    __shared__ __align__(16) u16 T32[8][64][40];   // 32 data + 8 pad
    const int tid = threadIdx.x, wave = tid >> 6, lane = tid & 63;
    const int col = lane & 15, quad = lane >> 4;
    const int mbase = blockIdx.x * 64, b = blockIdx.x >> 3;
    const int mh = (wave & 1) * 32, nh = (wave >> 1) * 32;

    // phase A: T = gelu(A5 @ Wo0t)
    {
        f32x4 acc[4][2][2];
#pragma unroll
        for (int nt = 0; nt < 4; ++nt)
#pragma unroll
            for (int i = 0; i < 2; ++i)
#pragma unroll
                for (int j = 0; j < 2; ++j) acc[nt][i][j] = (f32x4){0.f, 0.f, 0.f, 0.f};
        for (int kc = 0; kc < 8; ++kc) {
            short8 af[2];
#pragma unroll
            for (int i = 0; i < 2; ++i)
                af[i] = *(const short8*)(A5 + (size_t)(mbase + mh + i * 16 + col) * DD + kc * 32 + quad * 8);
#pragma unroll
            for (int nt = 0; nt < 4; ++nt) {
                short8 bfr[2];
#pragma unroll
                for (int j = 0; j < 2; ++j)
                    bfr[j] = *(const short8*)(Wo0t + (size_t)(nt * 64 + nh + j * 16 + col) * DD + kc * 32 + quad * 8);
#pragma unroll
                for (int i = 0; i < 2; ++i)
#pragma unroll
                    for (int j = 0; j < 2; ++j)
                        acc[nt][i][j] = __builtin_amdgcn_mfma_f32_16x16x32_bf16(af[i], bfr[j], acc[nt][i][j], 0, 0, 0);
            }
        }
#pragma unroll
        for (int nt = 0; nt < 4; ++nt)
#pragma unroll
            for (int i = 0; i < 2; ++i)
#pragma unroll
                for (int j = 0; j < 2; ++j) {
                    const int ccol = nt * 64 + nh + j * 16 + col;
#pragma unroll
                    for (int r = 0; r < 4; ++r) {
                        const int row = mh + i * 16 + quad * 4 + r;
                        T32[ccol >> 5][row][ccol & 31] = f2bf(gelu_f(acc[nt][i][j][r]));
                    }
                }
    }
    __syncthreads();

    // phase B: Q/K/V = T @ W
    const u16* Ws[3] = {Wq1t, Wk1t, Wv1t};
    for (int sel = 0; sel < 3; ++sel) {
        const u16* W = Ws[sel];
        f32x4 acc[4][2][2];
#pragma unroll
        for (int nt = 0; nt < 4; ++nt)
#pragma unroll
            for (int i = 0; i < 2; ++i)
#pragma unroll
                for (int j = 0; j < 2; ++j) acc[nt][i][j] = (f32x4){0.f, 0.f, 0.f, 0.f};
        for (int kc = 0; kc < 8; ++kc) {
            short8 af[2];
#pragma unroll
            for (int i = 0; i < 2; ++i)
                af[i] = *(const short8*)&T32[kc][mh + i * 16 + col][quad * 8];
#pragma unroll
            for (int nt = 0; nt < 4; ++nt) {
                short8 bfr[2];
#pragma unroll
                for (int j = 0; j < 2; ++j)
                    bfr[j] = *(const short8*)(W + (size_t)(nt * 64 + nh + j * 16 + col) * DD + kc * 32 + quad * 8);
#pragma unroll
                for (int i = 0; i < 2; ++i)
#pragma unroll
                    for (int j = 0; j < 2; ++j)
                        acc[nt][i][j] = __builtin_amdgcn_mfma_f32_16x16x32_bf16(af[i], bfr[j], acc[nt][i][j], 0, 0, 0);
            }
        }
#pragma unroll
        for (int nt = 0; nt < 4; ++nt)
#pragma unroll
            for (int i = 0; i < 2; ++i)
#pragma unroll
                for (int j = 0; j < 2; ++j) {
                    const int ccol = nt * 64 + nh + j * 16 + col;
                    const int head = ccol >> 5, dk = ccol & 31;
                    const int tok0 = (mbase & 511) + mh + i * 16 + quad * 4;
                    if (sel == 2) {
                        ushort4 pk;
                        pk.x = f2bf(acc[nt][i][j][0]); pk.y = f2bf(acc[nt][i][j][1]);
                        pk.z = f2bf(acc[nt][i][j][2]); pk.w = f2bf(acc[nt][i][j][3]);
                        *(ushort4*)&VT[(((size_t)b * HH + head) * 32 + dk) * NN + tok0] = pk;
                    } else {
                        u16* O = (sel == 0) ? Qh : Kh;
#pragma unroll
                        for (int r = 0; r < 4; ++r) {
                            float v = acc[nt][i][j][r];
                            if (sel == 0) v *= QSCALE;
                            O[(((size_t)b * HH + head) * NN + tok0 + r) * 32 + dk] = f2bf(v);
                        }
                    }
                }
    }
}

// ---------------------------------------------------------------------------
// Fused H + F for 64 rows/block (grid 128). Phase A: H = gelu(G@W1b+tvec+b1)
// into LDS. Phase B: F = H @ W2 + b2 (fp32 out).
// ---------------------------------------------------------------------------
__global__ __launch_bounds__(256) void fused_hf(
    const u16* __restrict__ G, const u16* __restrict__ W1t,
    const u16* __restrict__ W2t, const float* __restrict__ b1,
    const float* __restrict__ tvec, const float* __restrict__ b2,
    float* __restrict__ OF)
{
    __shared__ __align__(16) u16 T32[8][64][40];
    const int tid = threadIdx.x, wave = tid >> 6, lane = tid & 63;
    const int col = lane & 15, quad = lane >> 4;
    const int mbase = blockIdx.x * 64, b = blockIdx.x >> 3;
    const int mh = (wave & 1) * 32, nh = (wave >> 1) * 32;

    {
        f32x4 acc[4][2][2];
#pragma unroll
        for (int nt = 0; nt < 4; ++nt)
#pragma unroll
            for (int i = 0; i < 2; ++i)
#pragma unroll
                for (int j = 0; j < 2; ++j) acc[nt][i][j] = (f32x4){0.f, 0.f, 0.f, 0.f};
        for (int kc = 0; kc < 8; ++kc) {
            short8 af[2];
#pragma unroll
            for (int i = 0; i < 2; ++i)
                af[i] = *(const short8*)(G + (size_t)(mbase + mh + i * 16 + col) * DD + kc * 32 + quad * 8);
#pragma unroll
            for (int nt = 0; nt < 4; ++nt) {
                short8 bfr[2];
#pragma unroll
                for (int j = 0; j < 2; ++j)
                    bfr[j] = *(const short8*)(W1t + (size_t)(nt * 64 + nh + j * 16 + col) * DD + kc * 32 + quad * 8);
#pragma unroll
                for (int i = 0; i < 2; ++i)
#pragma unroll
                    for (int j = 0; j < 2; ++j)
                        acc[nt][i][j] = __builtin_amdgcn_mfma_f32_16x16x32_bf16(af[i], bfr[j], acc[nt][i][j], 0, 0, 0);
            }
        }
#pragma unroll
        for (int nt = 0; nt < 4; ++nt)
#pragma unroll
            for (int i = 0; i < 2; ++i)
#pragma unroll
                for (int j = 0; j < 2; ++j) {
                    const int ccol = nt * 64 + nh + j * 16 + col;
                    const float add = b1[ccol] + tvec[b * DD + ccol];
#pragma unroll
                    for (int r = 0; r < 4; ++r) {
                        const int row = mh + i * 16 + quad * 4 + r;
                        T32[ccol >> 5][row][ccol & 31] = f2bf(gelu_f(acc[nt][i][j][r] + add));
                    }
                }
    }
    __syncthreads();

    {
        f32x4 acc[4][2][2];
#pragma unroll
        for (int nt = 0; nt < 4; ++nt)
#pragma unroll
            for (int i = 0; i < 2; ++i)
#pragma unroll
                for (int j = 0; j < 2; ++j) acc[nt][i][j] = (f32x4){0.f, 0.f, 0.f, 0.f};
        for (int kc = 0; kc < 8; ++kc) {
            short8 af[2];
#pragma unroll
            for (int i = 0; i < 2; ++i)
                af[i] = *(const short8*)&T32[kc][mh + i * 16 + col][quad * 8];
#pragma unroll
            for (int nt = 0; nt < 4; ++nt) {
                short8 bfr[2];
#pragma unroll
                for (int j = 0; j < 2; ++j)
                    bfr[j] = *(const short8*)(W2t + (size_t)(nt * 64 + nh + j * 16 + col) * DD + kc * 32 + quad * 8);
#pragma unroll
                for (int i = 0; i < 2; ++i)
#pragma unroll
                    for (int j = 0; j < 2; ++j)
                        acc[nt][i][j] = __builtin_amdgcn_mfma_f32_16x16x32_bf16(af[i], bfr[j], acc[nt][i][j], 0, 0, 0);
            }
        }
#pragma unroll
        for (int nt = 0; nt < 4; ++nt)
#pragma unroll
            for (int i = 0; i < 2; ++i)
#pragma unroll
                for (int j = 0; j < 2; ++j) {
                    const int ccol = nt * 64 + nh + j * 16 + col;
                    const float bb = b2[ccol];
#pragma unroll
                    for (int r = 0; r < 4; ++r) {
                        const int crow = mbase + mh + i * 16 + quad * 4 + r;
                        OF[(size_t)crow * DD + ccol] = acc[nt][i][j][r] + bb;
                    }
                }
    }
}

// ---------------------------------------------------------------------------
__global__ __launch_bounds__(256) void convert_all(
    const float* __restrict__ e, u16* __restrict__ E, u16* __restrict__ G,
    const float* s0, const float* s1, const float* s2, const float* s3,
    const float* s4, const float* s5, const float* s6, const float* s7,
    const float* s8, u16* __restrict__ Wt)
{
    const int bx = blockIdx.x;
    if (bx < 2048) {
        const size_t i = ((size_t)bx * 256 + threadIdx.x) * 4;
        const float4 v = *(const float4*)(e + i);
        ushort4 ev, gv;
        ev.x = f2bf(v.x); ev.y = f2bf(v.y); ev.z = f2bf(v.z); ev.w = f2bf(v.w);
        gv.x = f2bf(gelu_f(v.x)); gv.y = f2bf(gelu_f(v.y));
        gv.z = f2bf(gelu_f(v.z)); gv.w = f2bf(gelu_f(v.w));
        *(ushort4*)(E + i) = ev;
        *(ushort4*)(G + i) = gv;
    } else {
        const int w = bx - 2048;
        const int my = w >> 4, kb = (w & 15) * 16;
        const int n = threadIdx.x;
        const float* S;
        switch (my) {
            case 0: S = s0; break; case 1: S = s1; break; case 2: S = s2; break;
            case 3: S = s3; break; case 4: S = s4; break; case 5: S = s5; break;
            case 6: S = s6; break; case 7: S = s7; break; default: S = s8; break;
        }
        u16* Dst = Wt + (size_t)my * 65536;
        for (int r = 0; r < 16; ++r) {
            const int k = kb + r;
            Dst[(size_t)n * 256 + k] = f2bf(S[(size_t)k * 256 + n]);
        }
    }
}

// ---------------------------------------------------------------------------
// latency-unrolled matvec: 8 independent accumulator chains
// ---------------------------------------------------------------------------
__device__ __forceinline__ float mv256(const float* __restrict__ a,
                                       const float* __restrict__ W, int d)
{
    float acc[8] = {0.f, 0.f, 0.f, 0.f, 0.f, 0.f, 0.f, 0.f};
    for (int k = 0; k < 256; k += 8) {
#pragma unroll
        for (int j = 0; j < 8; ++j)
            acc[j] += a[k + j] * W[(size_t)(k + j) * 256 + d];
    }
    return ((acc[0] + acc[1]) + (acc[2] + acc[3])) + ((acc[4] + acc[5]) + (acc[6] + acc[7]));
}

// aggr: m1=mean(attn1 colsums); a1=gelu(m1@Wo1); a2=gelu(a1@resW+resb);
// tvec=a2@ffW1[0:256]; also counts histogram. grid BB.
__global__ __launch_bounds__(256) void aggr_v2(
    const float* __restrict__ partial, const float* __restrict__ Wo1f,
    const float* __restrict__ resW, const float* __restrict__ resb,
    const float* __restrict__ W1, const int* __restrict__ labels,
    float* __restrict__ tvec, float* __restrict__ counts)
{
    const int b = blockIdx.x, d = threadIdx.x;
    __shared__ float a0[256], a1[256], a2[256];
    __shared__ int hist[CC];
    if (d < CC) hist[d] = 0;
    const int h = d >> 5, d32 = d & 31;
    float s = 0.f;
#pragma unroll
    for (int qb = 0; qb < 8; ++qb)
        s += partial[(size_t)(((b * 8 + h) * 8) + qb) * 32 + d32];
    a0[d] = s * (1.0f / NN);
    __syncthreads();
    atomicAdd(&hist[labels[b * NN + d]], 1);
    atomicAdd(&hist[labels[b * NN + 256 + d]], 1);
    a1[d] = gelu_f(mv256(a0, Wo1f, d));
    __syncthreads();
    a2[d] = gelu_f(mv256(a1, resW, d) + resb[d]);
    __syncthreads();
    tvec[b * 256 + d] = mv256(a2, W1, d);
    if (d < CC) counts[b * CC + d] = (float)hist[d];
}

// ---------------------------------------------------------------------------
// class sums: branchless per-thread 16-class register accumulation.
// grid (BB, 4 dchunks); thread = (row-group w, dim lane).
// ---------------------------------------------------------------------------
__global__ __launch_bounds__(256) void classsum_v2(
    const float* __restrict__ F, const int* __restrict__ labels,
    float* __restrict__ g)
{
    const int b = blockIdx.x, dch = blockIdx.y;
    const int t = threadIdx.x, w = t >> 6, lane = t & 63;
    __shared__ int lab[NN];
    __shared__ float gs[4][CC][64];
    lab[t] = labels[b * NN + t];
    lab[t + 256] = labels[b * NN + t + 256];
    __syncthreads();
    float acc[CC];
#pragma unroll
    for (int c = 0; c < CC; ++c) acc[c] = 0.f;
    const float* Fb = F + (size_t)b * NN * DD + dch * 64 + lane;
#pragma unroll 4
    for (int n = w * 128; n < w * 128 + 128; ++n) {
        const float v = Fb[(size_t)n * DD];
        const int lb = lab[n];
#pragma unroll
        for (int c = 0; c < CC; ++c) acc[c] += (lb == c) ? v : 0.f;
    }
#pragma unroll
    for (int c = 0; c < CC; ++c) gs[w][c][lane] = acc[c];
    __syncthreads();
#pragma unroll
    for (int i = 0; i < 4; ++i) {
        const int c = w * 4 + i;
        g[((size_t)b * CC + c) * DD + dch * 64 + lane] =
            gs[0][c][lane] + gs[1][c][lane] + gs[2][c][lane] + gs[3][c][lane];
    }
}

__global__ __launch_bounds__(256) void out_kernel(
    const float* __restrict__ F, const int* __restrict__ labels,
    const float* __restrict__ g, const float* __restrict__ counts,
    float* __restrict__ out)
{
    const int b = blockIdx.y;
    const int wave = threadIdx.x >> 6, lane = threadIdx.x & 63;
    const int n = blockIdx.x * 4 + wave;
    const float* fn = F + ((size_t)b * NN + n) * DD;
    const float* gb = g + (size_t)b * CC * DD;
    float fv[4];
#pragma unroll
    for (int i = 0; i < 4; ++i) fv[i] = fn[lane * 4 + i];
    float selfdot = 0.f;
#pragma unroll
    for (int i = 0; i < 4; ++i) selfdot += fv[i] * fv[i];
    float accs[CC];
#pragma unroll
    for (int c = 0; c < CC; ++c) {
        float sacc = 0.f;
#pragma unroll
        for (int i = 0; i < 4; ++i) sacc += fv[i] * gb[c * DD + lane * 4 + i];
        accs[c] = sacc;
    }
    for (int off = 32; off; off >>= 1) {
        selfdot += __shfl_xor(selfdot, off, 64);
#pragma unroll
        for (int c = 0; c < CC; ++c) accs[c] += __shfl_xor(accs[c], off, 64);
    }
    if (lane < CC) {
        const int c = lane;
        const int same = (labels[b * NN + n] == c) ? 1 : 0;
        const float num = accs[c] - (same ? selfdot : 0.f);
        const float den = counts[b * CC + c] - (float)same;
        out[((size_t)b * NN + n) * CC + c] = num / den;
    }
}

// ---------------------------------------------------------------------------
extern "C" void kernel_launch(void* const* d_in, const int* in_sizes, int n_in,
                              void* d_out, int out_size, void* d_ws, size_t ws_size,
                              hipStream_t stream)
{
    const float* emb    = (const float*)d_in[0];
    const int*   labels = (const int*)  d_in[1];
    const float* Wo1f = (const float*)d_in[9];
    const float* resW = (const float*)d_in[10];
    const float* resb = (const float*)d_in[11];
    const float* ffW1 = (const float*)d_in[12];
    const float* ffb1 = (const float*)d_in[13];
    const float* ffb2 = (const float*)d_in[15];
    float* out = (float*)d_out;

    const size_t SBE = (size_t)BB * NN * DD;
    u16* BUF0 = (u16*)d_ws;          // E_bf
    u16* BUF1 = BUF0 + SBE;          // gelu(emb) bf16
    u16* BUF2 = BUF1 + SBE;          // Qh [b,h,n,32]
    u16* BUF3 = BUF2 + SBE;          // Kh
    u16* BUF4 = BUF3 + SBE;          // VT [b,h,32,n]
    u16* BUF5 = BUF4 + SBE;          // attn0 out (token-major)
    u16* Wt   = BUF5 + SBE;          // 9 x [256n x 256k] bf16 transposed
    float* F      = (float*)(Wt + 9 * 65536);   // [8192x256] fp32 features
    float* tvec   = F + SBE;
    float* partial= tvec + BB * 256;            // [128 bh][8 qb][32]
    float* gsum   = partial + 128 * 8 * 32;
    float* counts = gsum + (size_t)BB * CC * DD;

    convert_all<<<2048 + 144, 256, 0, stream>>>(
        emb, BUF0, BUF1,
        (const float*)d_in[2], (const float*)d_in[3], (const float*)d_in[4],
        (const float*)d_in[5], (const float*)d_in[6], (const float*)d_in[7],
        (const float*)d_in[8], ffW1 + 256 * 256, (const float*)d_in[14], Wt);
    gemm_qkv<<<dim3(128, 12), 256, 0, stream>>>(
        BUF0, Wt, Wt + 65536, Wt + 2 * 65536, BUF2, BUF3, BUF4);
    attn_mfma<0><<<1024, 256, 0, stream>>>(BUF2, BUF3, BUF4, BUF5, nullptr);
    fused_x1qkv1<<<128, 256, 0, stream>>>(
        BUF5, Wt + 3 * 65536, Wt + 4 * 65536, Wt + 5 * 65536, Wt + 6 * 65536,
        BUF2, BUF3, BUF4);
    attn_mfma<1><<<1024, 256, 0, stream>>>(BUF2, BUF3, BUF4, nullptr, partial);
    aggr_v2<<<BB, 256, 0, stream>>>(partial, Wo1f, resW, resb, ffW1, labels, tvec, counts);
    fused_hf<<<128, 256, 0, stream>>>(
        BUF1, Wt + 7 * 65536, Wt + 8 * 65536, ffb1, tvec, ffb2, F);
    classsum_v2<<<dim3(BB, 4), 256, 0, stream>>>(F, labels, gsum);
    out_kernel<<<dim3(128, BB), 256, 0, stream>>>(F, labels, gsum, counts, out);
}

// Round 6
// 211.161 us; speedup vs baseline: 1.2503x; 1.2503x over previous
//
#include <hip/hip_runtime.h>

#define BB 16
#define NN 512
#define DD 256
#define HH 8
#define CC 16

typedef unsigned short u16;
using short8 = __attribute__((ext_vector_type(8))) short;
using f32x4  = __attribute__((ext_vector_type(4))) float;

__device__ __forceinline__ float gelu_f(float x) {
    return 0.5f * x * (1.0f + erff(x * 0.70710678118654752f));
}
__device__ __forceinline__ u16 f2bf(float f) {
    unsigned int u = __float_as_uint(f);
    unsigned int r = u + 0x7FFFu + ((u >> 16) & 1u);
    return (u16)(r >> 16);
}
// async global->LDS, 16B/lane; LDS dest = wave-uniform base + lane*16
__device__ __forceinline__ void gld16(const u16* g, const u16* l) {
    __builtin_amdgcn_global_load_lds(
        (const __attribute__((address_space(1))) unsigned int*)g,
        (__attribute__((address_space(3))) unsigned int*)l, 16, 0, 0);
}

// Q pre-scale: (1/sqrt(32)) * log2(e)  -> attention uses exp2
#define QSCALE 0.25505412f

// ---------------------------------------------------------------------------
// Generic 64x64-tile bf16 MFMA GEMM (BK=32, LDS staging). grid (128, 4).
// O = act(A @ Wt + bias + tvec[b]); token-major bf16 or fp32 out.
// ---------------------------------------------------------------------------
template<int ACT, int HAS_B, int HAS_T, int OUT_F32>
__global__ __launch_bounds__(256) void gemm64(
    const u16* __restrict__ A, const u16* __restrict__ W,
    u16* __restrict__ O, float* __restrict__ OF,
    const float* __restrict__ bias, const float* __restrict__ tvec)
{
    __shared__ __align__(16) u16 As[64 * 32];
    __shared__ __align__(16) u16 Bs[64 * 32];
    const int tid = threadIdx.x, wave = tid >> 6, lane = tid & 63;
    const int col = lane & 15, quad = lane >> 4;
    const int mbase = blockIdx.x * 64;
    const int nbase = blockIdx.y * 64;
    const int srow = lane >> 2, skk = (lane & 3) * 8;
    const int mh = (wave & 1) * 32, nh = (wave >> 1) * 32;

    f32x4 acc[2][2];
#pragma unroll
    for (int i = 0; i < 2; ++i)
#pragma unroll
        for (int j = 0; j < 2; ++j) acc[i][j] = (f32x4){0.f, 0.f, 0.f, 0.f};

    for (int k0 = 0; k0 < DD; k0 += 32) {
        gld16(A + (size_t)(mbase + wave * 16 + srow) * DD + k0 + skk, &As[wave * 512]);
        gld16(W + (size_t)(nbase + wave * 16 + srow) * DD + k0 + skk, &Bs[wave * 512]);
        __syncthreads();
        short8 af[2], bfr[2];
#pragma unroll
        for (int i = 0; i < 2; ++i) af[i]  = *(const short8*)&As[(mh + i * 16 + col) * 32 + quad * 8];
#pragma unroll
        for (int j = 0; j < 2; ++j) bfr[j] = *(const short8*)&Bs[(nh + j * 16 + col) * 32 + quad * 8];
#pragma unroll
        for (int i = 0; i < 2; ++i)
#pragma unroll
            for (int j = 0; j < 2; ++j)
                acc[i][j] = __builtin_amdgcn_mfma_f32_16x16x32_bf16(af[i], bfr[j], acc[i][j], 0, 0, 0);
        __syncthreads();
    }

    const int b = mbase >> 9;
#pragma unroll
    for (int i = 0; i < 2; ++i) {
#pragma unroll
        for (int j = 0; j < 2; ++j) {
            const int ccol = nbase + nh + j * 16 + col;
#pragma unroll
            for (int r = 0; r < 4; ++r) {
                const int crow = mbase + mh + i * 16 + quad * 4 + r;
                float v = acc[i][j][r];
                if (HAS_B) v += bias[ccol];
                if (HAS_T) v += tvec[b * DD + ccol];
                if (ACT)   v = gelu_f(v);
                if (OUT_F32) OF[(size_t)crow * DD + ccol] = v;
                else         O[(size_t)crow * DD + ccol] = f2bf(v);
            }
        }
    }
}

// ---------------------------------------------------------------------------
// QKV GEMM: 64x64 tiles, BK=32, LDS staging. grid (128, 12).
// sel = y>>2 picks Q/K/V; Q,K head-major [b,h,n,32] (Q scaled), V [b,h,32,n].
// ---------------------------------------------------------------------------
__global__ __launch_bounds__(256) void gemm_qkv(
    const u16* __restrict__ A,
    const u16* __restrict__ W0, const u16* __restrict__ W1, const u16* __restrict__ W2,
    u16* __restrict__ O0, u16* __restrict__ O1, u16* __restrict__ O2)
{
    __shared__ __align__(16) u16 As[64 * 32];
    __shared__ __align__(16) u16 Bs[64 * 32];
    const int tid = threadIdx.x, wave = tid >> 6, lane = tid & 63;
    const int col = lane & 15, quad = lane >> 4;
    const int mbase = blockIdx.x * 64;
    const int sel = blockIdx.y >> 2;
    const int nbase = (blockIdx.y & 3) * 64;
    const u16* W = (sel == 0) ? W0 : ((sel == 1) ? W1 : W2);
    u16* O = (sel == 0) ? O0 : ((sel == 1) ? O1 : O2);
    const int srow = lane >> 2, skk = (lane & 3) * 8;
    const int mh = (wave & 1) * 32, nh = (wave >> 1) * 32;

    f32x4 acc[2][2];
#pragma unroll
    for (int i = 0; i < 2; ++i)
#pragma unroll
        for (int j = 0; j < 2; ++j) acc[i][j] = (f32x4){0.f, 0.f, 0.f, 0.f};

    for (int k0 = 0; k0 < DD; k0 += 32) {
        gld16(A + (size_t)(mbase + wave * 16 + srow) * DD + k0 + skk, &As[wave * 512]);
        gld16(W + (size_t)(nbase + wave * 16 + srow) * DD + k0 + skk, &Bs[wave * 512]);
        __syncthreads();
        short8 af[2], bfr[2];
#pragma unroll
        for (int i = 0; i < 2; ++i) af[i]  = *(const short8*)&As[(mh + i * 16 + col) * 32 + quad * 8];
#pragma unroll
        for (int j = 0; j < 2; ++j) bfr[j] = *(const short8*)&Bs[(nh + j * 16 + col) * 32 + quad * 8];
#pragma unroll
        for (int i = 0; i < 2; ++i)
#pragma unroll
            for (int j = 0; j < 2; ++j)
                acc[i][j] = __builtin_amdgcn_mfma_f32_16x16x32_bf16(af[i], bfr[j], acc[i][j], 0, 0, 0);
        __syncthreads();
    }

    const int b = mbase >> 9;
#pragma unroll
    for (int i = 0; i < 2; ++i) {
#pragma unroll
        for (int j = 0; j < 2; ++j) {
            const int ccol = nbase + nh + j * 16 + col;
            const int tok0 = (mbase & 511) + mh + i * 16 + quad * 4;
            const int head = ccol >> 5, dk = ccol & 31;
            if (sel == 2) {
                ushort4 pk;
                pk.x = f2bf(acc[i][j][0]); pk.y = f2bf(acc[i][j][1]);
                pk.z = f2bf(acc[i][j][2]); pk.w = f2bf(acc[i][j][3]);
                *(ushort4*)&O[(((size_t)b * HH + head) * 32 + dk) * NN + tok0] = pk;
            } else {
#pragma unroll
                for (int r = 0; r < 4; ++r) {
                    float v = acc[i][j][r];
                    if (sel == 0) v *= QSCALE;
                    O[(((size_t)b * HH + head) * NN + tok0 + r) * 32 + dk] = f2bf(v);
                }
            }
        }
    }
}

// ---------------------------------------------------------------------------
// Flash MFMA attention, no-max softmax (pre-scaled by log2e/sqrt(dk), exp2).
// grid 1024: gid = qb*128 + (b*8+h) -> q-blocks of a (b,h) share an XCD.
// COLSUM=1: only writes per-block column sums (feeds mean(x2)@Wo1).
// ---------------------------------------------------------------------------
template<int COLSUM>
__global__ __launch_bounds__(256) void attn_mfma(
    const u16* __restrict__ Qh, const u16* __restrict__ Kh,
    const u16* __restrict__ VT, u16* __restrict__ O,
    float* __restrict__ partial)
{
    __shared__ __align__(16) u16 Vt[32 * 520];
    __shared__ __align__(16) u16 Pc[4][16 * 32];
    __shared__ float cs[4][32];
    const int tid = threadIdx.x, wave = tid >> 6, lane = tid & 63;
    const int col = lane & 15, quad = lane >> 4;
    const int gid = blockIdx.x;
    const int qb = gid >> 7, bh = gid & 127;
    const int q0 = qb * 64 + wave * 16;

    const u16* vsrc = VT + (size_t)bh * 32 * NN;
#pragma unroll
    for (int i = 0; i < 8; ++i) {
        const int row = wave + i * 4;
        gld16(vsrc + (size_t)row * NN + lane * 8, &Vt[row * 520]);
    }
    const short8 aq = *(const short8*)(Qh + ((size_t)bh * NN + q0 + col) * 32 + quad * 8);
    __syncthreads();

    const u16* ksrc = Kh + (size_t)bh * NN * 32;
    float l[4] = {0.f, 0.f, 0.f, 0.f};
    f32x4 oacc[2];
    oacc[0] = (f32x4){0.f, 0.f, 0.f, 0.f};
    oacc[1] = (f32x4){0.f, 0.f, 0.f, 0.f};

    for (int g = 0; g < 16; ++g) {
#pragma unroll
        for (int k2 = 0; k2 < 2; ++k2) {
            const int kt = g * 2 + k2;
            const short8 bk = *(const short8*)(ksrc + (size_t)(kt * 16 + col) * 32 + quad * 8);
            f32x4 z = {0.f, 0.f, 0.f, 0.f};
            const f32x4 s = __builtin_amdgcn_mfma_f32_16x16x32_bf16(aq, bk, z, 0, 0, 0);
#pragma unroll
            for (int r = 0; r < 4; ++r) {
                const float p = exp2f(s[r]);
                l[r] += p;
                Pc[wave][(quad * 4 + r) * 32 + k2 * 16 + col] = f2bf(p);
            }
        }
        const short8 ap = *(const short8*)&Pc[wave][col * 32 + quad * 8];
#pragma unroll
        for (int nt = 0; nt < 2; ++nt) {
            const short8 bv = *(const short8*)&Vt[(nt * 16 + col) * 520 + g * 32 + quad * 8];
            oacc[nt] = __builtin_amdgcn_mfma_f32_16x16x32_bf16(ap, bv, oacc[nt], 0, 0, 0);
        }
    }
#pragma unroll
    for (int r = 0; r < 4; ++r) {
        l[r] += __shfl_xor(l[r], 1, 64);
        l[r] += __shfl_xor(l[r], 2, 64);
        l[r] += __shfl_xor(l[r], 4, 64);
        l[r] += __shfl_xor(l[r], 8, 64);
    }
    if (COLSUM) {
        float sv[2] = {0.f, 0.f};
#pragma unroll
        for (int nt = 0; nt < 2; ++nt) {
#pragma unroll
            for (int r = 0; r < 4; ++r) sv[nt] += oacc[nt][r] / l[r];
            sv[nt] += __shfl_xor(sv[nt], 16, 64);
            sv[nt] += __shfl_xor(sv[nt], 32, 64);
        }
        if (lane < 16) { cs[wave][col] = sv[0]; cs[wave][16 + col] = sv[1]; }
        __syncthreads();
        if (tid < 32)
            partial[(size_t)(bh * 8 + qb) * 32 + tid] =
                cs[0][tid] + cs[1][tid] + cs[2][tid] + cs[3][tid];
    } else {
        const int b = bh >> 3, h = bh & 7;
        u16* obase = O + ((size_t)b * NN) * DD + h * 32;
#pragma unroll
        for (int nt = 0; nt < 2; ++nt)
#pragma unroll
            for (int r = 0; r < 4; ++r)
                obase[(size_t)(q0 + quad * 4 + r) * DD + nt * 16 + col] = f2bf(oacc[nt][r] / l[r]);
    }
}

// ---------------------------------------------------------------------------
__global__ __launch_bounds__(256) void convert_all(
    const float* __restrict__ e, u16* __restrict__ E, u16* __restrict__ G,
    const float* s0, const float* s1, const float* s2, const float* s3,
    const float* s4, const float* s5, const float* s6, const float* s7,
    const float* s8, u16* __restrict__ Wt)
{
    const int bx = blockIdx.x;
    if (bx < 2048) {
        const size_t i = ((size_t)bx * 256 + threadIdx.x) * 4;
        const float4 v = *(const float4*)(e + i);
        ushort4 ev, gv;
        ev.x = f2bf(v.x); ev.y = f2bf(v.y); ev.z = f2bf(v.z); ev.w = f2bf(v.w);
        gv.x = f2bf(gelu_f(v.x)); gv.y = f2bf(gelu_f(v.y));
        gv.z = f2bf(gelu_f(v.z)); gv.w = f2bf(gelu_f(v.w));
        *(ushort4*)(E + i) = ev;
        *(ushort4*)(G + i) = gv;
    } else {
        const int w = bx - 2048;
        const int my = w >> 4, kb = (w & 15) * 16;
        const int n = threadIdx.x;
        const float* S;
        switch (my) {
            case 0: S = s0; break; case 1: S = s1; break; case 2: S = s2; break;
            case 3: S = s3; break; case 4: S = s4; break; case 5: S = s5; break;
            case 6: S = s6; break; case 7: S = s7; break; default: S = s8; break;
        }
        u16* Dst = Wt + (size_t)my * 65536;
        for (int r = 0; r < 16; ++r) {
            const int k = kb + r;
            Dst[(size_t)n * 256 + k] = f2bf(S[(size_t)k * 256 + n]);
        }
    }
}

// ---------------------------------------------------------------------------
// latency-unrolled matvec: 8 independent accumulator chains
// ---------------------------------------------------------------------------
__device__ __forceinline__ float mv256(const float* __restrict__ a,
                                       const float* __restrict__ W, int d)
{
    float acc[8] = {0.f, 0.f, 0.f, 0.f, 0.f, 0.f, 0.f, 0.f};
    for (int k = 0; k < 256; k += 8) {
#pragma unroll
        for (int j = 0; j < 8; ++j)
            acc[j] += a[k + j] * W[(size_t)(k + j) * 256 + d];
    }
    return ((acc[0] + acc[1]) + (acc[2] + acc[3])) + ((acc[4] + acc[5]) + (acc[6] + acc[7]));
}

// aggr: m1=mean(attn1 colsums); a1=gelu(m1@Wo1); a2=gelu(a1@resW+resb);
// tvec=a2@ffW1[0:256]; also counts histogram. grid BB.
__global__ __launch_bounds__(256) void aggr_v2(
    const float* __restrict__ partial, const float* __restrict__ Wo1f,
    const float* __restrict__ resW, const float* __restrict__ resb,
    const float* __restrict__ W1, const int* __restrict__ labels,
    float* __restrict__ tvec, float* __restrict__ counts)
{
    const int b = blockIdx.x, d = threadIdx.x;
    __shared__ float a0[256], a1[256], a2[256];
    __shared__ int hist[CC];
    if (d < CC) hist[d] = 0;
    const int h = d >> 5, d32 = d & 31;
    float s = 0.f;
#pragma unroll
    for (int qb = 0; qb < 8; ++qb)
        s += partial[(size_t)(((b * 8 + h) * 8) + qb) * 32 + d32];
    a0[d] = s * (1.0f / NN);
    __syncthreads();
    atomicAdd(&hist[labels[b * NN + d]], 1);
    atomicAdd(&hist[labels[b * NN + 256 + d]], 1);
    a1[d] = gelu_f(mv256(a0, Wo1f, d));
    __syncthreads();
    a2[d] = gelu_f(mv256(a1, resW, d) + resb[d]);
    __syncthreads();
    tvec[b * 256 + d] = mv256(a2, W1, d);
    if (d < CC) counts[b * CC + d] = (float)hist[d];
}

// ---------------------------------------------------------------------------
// class sums: branchless per-thread 16-class register accumulation.
// grid (BB, 4 dchunks).
// ---------------------------------------------------------------------------
__global__ __launch_bounds__(256) void classsum_v2(
    const float* __restrict__ F, const int* __restrict__ labels,
    float* __restrict__ g)
{
    const int b = blockIdx.x, dch = blockIdx.y;
    const int t = threadIdx.x, w = t >> 6, lane = t & 63;
    __shared__ int lab[NN];
    __shared__ float gs[4][CC][64];
    lab[t] = labels[b * NN + t];
    lab[t + 256] = labels[b * NN + t + 256];
    __syncthreads();
    float acc[CC];
#pragma unroll
    for (int c = 0; c < CC; ++c) acc[c] = 0.f;
    const float* Fb = F + (size_t)b * NN * DD + dch * 64 + lane;
#pragma unroll 4
    for (int n = w * 128; n < w * 128 + 128; ++n) {
        const float v = Fb[(size_t)n * DD];
        const int lb = lab[n];
#pragma unroll
        for (int c = 0; c < CC; ++c) acc[c] += (lb == c) ? v : 0.f;
    }
#pragma unroll
    for (int c = 0; c < CC; ++c) gs[w][c][lane] = acc[c];
    __syncthreads();
#pragma unroll
    for (int i = 0; i < 4; ++i) {
        const int c = w * 4 + i;
        g[((size_t)b * CC + c) * DD + dch * 64 + lane] =
            gs[0][c][lane] + gs[1][c][lane] + gs[2][c][lane] + gs[3][c][lane];
    }
}

__global__ __launch_bounds__(256) void out_kernel(
    const float* __restrict__ F, const int* __restrict__ labels,
    const float* __restrict__ g, const float* __restrict__ counts,
    float* __restrict__ out)
{
    const int b = blockIdx.y;
    const int wave = threadIdx.x >> 6, lane = threadIdx.x & 63;
    const int n = blockIdx.x * 4 + wave;
    const float* fn = F + ((size_t)b * NN + n) * DD;
    const float* gb = g + (size_t)b * CC * DD;
    float fv[4];
#pragma unroll
    for (int i = 0; i < 4; ++i) fv[i] = fn[lane * 4 + i];
    float selfdot = 0.f;
#pragma unroll
    for (int i = 0; i < 4; ++i) selfdot += fv[i] * fv[i];
    float accs[CC];
#pragma unroll
    for (int c = 0; c < CC; ++c) {
        float sacc = 0.f;
#pragma unroll
        for (int i = 0; i < 4; ++i) sacc += fv[i] * gb[c * DD + lane * 4 + i];
        accs[c] = sacc;
    }
    for (int off = 32; off; off >>= 1) {
        selfdot += __shfl_xor(selfdot, off, 64);
#pragma unroll
        for (int c = 0; c < CC; ++c) accs[c] += __shfl_xor(accs[c], off, 64);
    }
    if (lane < CC) {
        const int c = lane;
        const int same = (labels[b * NN + n] == c) ? 1 : 0;
        const float num = accs[c] - (same ? selfdot : 0.f);
        const float den = counts[b * CC + c] - (float)same;
        out[((size_t)b * NN + n) * CC + c] = num / den;
    }
}

// ---------------------------------------------------------------------------
extern "C" void kernel_launch(void* const* d_in, const int* in_sizes, int n_in,
                              void* d_out, int out_size, void* d_ws, size_t ws_size,
                              hipStream_t stream)
{
    const float* emb    = (const float*)d_in[0];
    const int*   labels = (const int*)  d_in[1];
    const float* Wo1f = (const float*)d_in[9];
    const float* resW = (const float*)d_in[10];
    const float* resb = (const float*)d_in[11];
    const float* ffW1 = (const float*)d_in[12];
    const float* ffb1 = (const float*)d_in[13];
    const float* ffb2 = (const float*)d_in[15];
    float* out = (float*)d_out;

    const size_t SBE = (size_t)BB * NN * DD;
    u16* BUF0 = (u16*)d_ws;          // E_bf, later X1
    u16* BUF1 = BUF0 + SBE;          // gelu(emb) bf16
    u16* BUF2 = BUF1 + SBE;          // Qh [b,h,n,32]
    u16* BUF3 = BUF2 + SBE;          // Kh, later H
    u16* BUF4 = BUF3 + SBE;          // VT [b,h,32,n]
    u16* BUF5 = BUF4 + SBE;          // attn0 out (token-major)
    u16* Wt   = BUF5 + SBE;          // 9 x [256n x 256k] bf16 transposed
    float* F      = (float*)(Wt + 9 * 65536);   // [8192x256] fp32 features
    float* tvec   = F + SBE;
    float* partial= tvec + BB * 256;            // [128 bh][8 qb][32]
    float* gsum   = partial + 128 * 8 * 32;
    float* counts = gsum + (size_t)BB * CC * DD;

    convert_all<<<2048 + 144, 256, 0, stream>>>(
        emb, BUF0, BUF1,
        (const float*)d_in[2], (const float*)d_in[3], (const float*)d_in[4],
        (const float*)d_in[5], (const float*)d_in[6], (const float*)d_in[7],
        (const float*)d_in[8], ffW1 + 256 * 256, (const float*)d_in[14], Wt);
    // QKV0
    gemm_qkv<<<dim3(128, 12), 256, 0, stream>>>(
        BUF0, Wt, Wt + 65536, Wt + 2 * 65536, BUF2, BUF3, BUF4);
    attn_mfma<0><<<1024, 256, 0, stream>>>(BUF2, BUF3, BUF4, BUF5, nullptr);
    // X1 = gelu(attn0 @ Wo0) -> BUF0
    gemm64<1,0,0,0><<<dim3(128, 4), 256, 0, stream>>>(
        BUF5, Wt + 3 * 65536, BUF0, nullptr, nullptr, nullptr);
    // QKV1
    gemm_qkv<<<dim3(128, 12), 256, 0, stream>>>(
        BUF0, Wt + 4 * 65536, Wt + 5 * 65536, Wt + 6 * 65536, BUF2, BUF3, BUF4);
    // attn1: column sums only
    attn_mfma<1><<<1024, 256, 0, stream>>>(BUF2, BUF3, BUF4, nullptr, partial);
    aggr_v2<<<BB, 256, 0, stream>>>(partial, Wo1f, resW, resb, ffW1, labels, tvec, counts);
    // H = gelu(gelu(e) @ W1btm + tvec + b1) -> BUF3
    gemm64<1,1,1,0><<<dim3(128, 4), 256, 0, stream>>>(
        BUF1, Wt + 7 * 65536, BUF3, nullptr, ffb1, tvec);
    // F = H @ W2 + b2 (fp32)
    gemm64<0,1,0,1><<<dim3(128, 4), 256, 0, stream>>>(
        BUF3, Wt + 8 * 65536, nullptr, F, ffb2, nullptr);
    classsum_v2<<<dim3(BB, 4), 256, 0, stream>>>(F, labels, gsum);
    out_kernel<<<dim3(128, BB), 256, 0, stream>>>(F, labels, gsum, counts, out);
}